// Round 10
// baseline (195.060 us; speedup 1.0000x reference)
//
#include <hip/hip_runtime.h>
#include <hip/hip_bf16.h>

#define N_NODES 50000
#define N_EDGES 800000
#define IN_F    512
#define HEADS   8
#define DHEAD   32
#define NHD     256            // HEADS*DHEAD
#define SLOPE   0.2f
#define EPS_F   1e-16f
#define N_SBLK  ((N_NODES + 255) / 256)   // 196 scan blocks
#define NB_GEMM ((N_NODES + 63) / 64)     // 782 gemm blocks
#define NB_HIST ((N_EDGES + 4095) / 4096) // 196 hist blocks (4096 edges each)

typedef __attribute__((ext_vector_type(8))) short short8;
typedef __attribute__((ext_vector_type(4))) float f32x4;
typedef __attribute__((ext_vector_type(4))) unsigned short u16x4;
typedef __attribute__((ext_vector_type(4))) unsigned int u32x4;

__device__ __forceinline__ unsigned short f2bf(float f) {
  unsigned int u = __float_as_uint(f);
  unsigned int r = u + 0x7FFFu + ((u >> 16) & 1u);   // round-to-nearest-even
  return (unsigned short)(r >> 16);
}
__device__ __forceinline__ float bf2f(unsigned short s) {
  return __uint_as_float(((unsigned int)s) << 16);
}
// packed f32x2 -> bf16x2 (v_cvt_pk_bf16_f32, RNE)
__device__ __forceinline__ unsigned int pkbf(float a, float b) {
  __hip_bfloat162 t = __float22bfloat162_rn(float2{a, b});
  unsigned int r;
  __builtin_memcpy(&r, &t, sizeof(r));
  return r;
}
__device__ __forceinline__ void gload_lds16(const void* g, void* l) {
  __builtin_amdgcn_global_load_lds((const __attribute__((address_space(1))) void*)g,
                                   (__attribute__((address_space(3))) void*)l, 16, 0, 0);
}

// ---- cast W[h][k][d] (f32) -> WbT[c][k] (bf16), c = h*32+d; also zero deg
__global__ void k_cast_w(const float* __restrict__ W, unsigned short* __restrict__ WbT,
                         int* __restrict__ deg) {
  int id = blockIdx.x * blockDim.x + threadIdx.x;
  if (id < NHD * IN_F) {
    int c = id >> 9, k = id & 511;
    WbT[id] = f2bf(W[(c >> 5) * (IN_F * DHEAD) + k * DHEAD + (c & 31)]);
  }
  if (id < N_NODES) deg[id] = 0;
}

// ---- MFMA GEMM (blocks 0..781) + edge histogram (blocks 782..977).
// Tile 64(M)x256(N), BK=64, 4 waves (each 64x64 in N), single-buffer LDS.
// A-regs prefetched one K-step ahead (latency hides under compute);
// casts via v_cvt_pk_bf16_f32. LDS 16B k-quads at slot p = q ^ (row&7).
// Epilogue fuses s_src/s_dst score dots from f32 accumulators.
__global__ __launch_bounds__(256) void k_gemm_mfma(const float* __restrict__ x,
                                                   const unsigned short* __restrict__ WbT,
                                                   unsigned short* __restrict__ hb,
                                                   const float* __restrict__ a,
                                                   float* __restrict__ s_src,
                                                   float* __restrict__ s_dst,
                                                   const int* __restrict__ ei,
                                                   int* __restrict__ deg) {
  if (blockIdx.x >= NB_GEMM) {            // ---- histogram path (overlapped)
    int b = blockIdx.x - NB_GEMM;
    int end = min(b * 4096 + 4096, N_EDGES);
    for (int e = b * 4096 + threadIdx.x; e < end; e += 256)
      atomicAdd(&deg[ei[e]], 1);
    return;
  }

  __shared__ unsigned short As[64 * 64];    // 8 KB
  __shared__ unsigned short Bs[256 * 64];   // 32 KB
  const int tid  = threadIdx.x;
  const int lane = tid & 63;
  const int wid  = tid >> 6;
  const int bm   = blockIdx.x * 64;
  const int wn   = wid * 64;

  // A staging (reg + cast): slots tid and tid+256
  const int arow = tid >> 3, ap = tid & 7, aq = ap ^ (arow & 7);
  const float* gA0 = x + (size_t)min(bm + arow,      N_NODES - 1) * IN_F + aq * 8;
  const float* gA1 = x + (size_t)min(bm + arow + 32, N_NODES - 1) * IN_F + aq * 8;
  unsigned short* lA0 = &As[(arow * 8 + ap) * 8];
  unsigned short* lA1 = &As[((arow + 32) * 8 + ap) * 8];

  // B staging (async): wave wid stages slots 512*wid + 64*it + lane
  const int bs = 512 * wid + lane;
  const int brow = bs >> 3, bp = bs & 7, bq = bp ^ (brow & 7);
  const unsigned short* gB = WbT + (size_t)brow * IN_F + bq * 8;
  unsigned short* lB = &Bs[(size_t)512 * wid * 8];

  f32x4 acc[4][4] = {};
  float4 aA[2][4];

  // prologue: A regs for step 0
  aA[0][0] = *(const float4*)(gA0);
  aA[0][1] = *(const float4*)(gA0 + 4);
  aA[0][2] = *(const float4*)(gA1);
  aA[0][3] = *(const float4*)(gA1 + 4);

#pragma unroll
  for (int t = 0; t < 8; ++t) {
    const int k0 = t * 64;
    // stage B(t) async + write A(t) from prefetched regs
#pragma unroll
    for (int it = 0; it < 8; ++it)
      gload_lds16(gB + k0 + it * 8 * IN_F, lB + it * 64 * 8);
    {
      u32x4 v0 = { pkbf(aA[t & 1][0].x, aA[t & 1][0].y),
                   pkbf(aA[t & 1][0].z, aA[t & 1][0].w),
                   pkbf(aA[t & 1][1].x, aA[t & 1][1].y),
                   pkbf(aA[t & 1][1].z, aA[t & 1][1].w) };
      u32x4 v1 = { pkbf(aA[t & 1][2].x, aA[t & 1][2].y),
                   pkbf(aA[t & 1][2].z, aA[t & 1][2].w),
                   pkbf(aA[t & 1][3].x, aA[t & 1][3].y),
                   pkbf(aA[t & 1][3].z, aA[t & 1][3].w) };
      *(u32x4*)lA0 = v0;
      *(u32x4*)lA1 = v1;
    }
    __syncthreads();   // drains gload_lds B(t) + LDS writes

    // prefetch A regs for step t+1 (latency hides under compute(t))
    if (t < 7) {
      aA[(t + 1) & 1][0] = *(const float4*)(gA0 + k0 + 64);
      aA[(t + 1) & 1][1] = *(const float4*)(gA0 + k0 + 68);
      aA[(t + 1) & 1][2] = *(const float4*)(gA1 + k0 + 64);
      aA[(t + 1) & 1][3] = *(const float4*)(gA1 + k0 + 68);
    }

#pragma unroll
    for (int kk = 0; kk < 2; ++kk) {
      short8 af[4], bfr[4];
#pragma unroll
      for (int i = 0; i < 4; ++i) {
        int r = i * 16 + (lane & 15);
        int q = kk * 4 + (lane >> 4);
        af[i] = *(const short8*)&As[(r * 8 + (q ^ (r & 7))) * 8];
      }
#pragma unroll
      for (int j = 0; j < 4; ++j) {
        int r = wn + j * 16 + (lane & 15);
        int q = kk * 4 + (lane >> 4);
        bfr[j] = *(const short8*)&Bs[(r * 8 + (q ^ (r & 7))) * 8];
      }
#pragma unroll
      for (int i = 0; i < 4; ++i)
#pragma unroll
        for (int j = 0; j < 4; ++j)
          acc[i][j] = __builtin_amdgcn_mfma_f32_16x16x32_bf16(af[i], bfr[j], acc[i][j], 0, 0, 0);
    }
    __syncthreads();   // LDS consumed; safe to restage next step
  }

  // ---- epilogue: hb (bf16) write + fused scores from f32 acc
  // C/D layout: col = lane&15, row = (lane>>4)*4 + q
  const int h0 = 2 * wid, h1 = 2 * wid + 1;
  const int dl = lane & 15;
  const float as00 = a[h0 * 64 + dl],      as01 = a[h0 * 64 + 16 + dl];
  const float as10 = a[h1 * 64 + dl],      as11 = a[h1 * 64 + 16 + dl];
  const float ad00 = a[h0 * 64 + 32 + dl], ad01 = a[h0 * 64 + 48 + dl];
  const float ad10 = a[h1 * 64 + 32 + dl], ad11 = a[h1 * 64 + 48 + dl];

#pragma unroll
  for (int i = 0; i < 4; ++i) {
#pragma unroll
    for (int q = 0; q < 4; ++q) {
      int row = bm + i * 16 + (lane >> 4) * 4 + q;
      float ss0 = acc[i][0][q] * as00 + acc[i][1][q] * as01;
      float ss1 = acc[i][2][q] * as10 + acc[i][3][q] * as11;
      float sd0 = acc[i][0][q] * ad00 + acc[i][1][q] * ad01;
      float sd1 = acc[i][2][q] * ad10 + acc[i][3][q] * ad11;
#pragma unroll
      for (int o = 1; o < 16; o <<= 1) {
        ss0 += __shfl_xor(ss0, o);
        ss1 += __shfl_xor(ss1, o);
        sd0 += __shfl_xor(sd0, o);
        sd1 += __shfl_xor(sd1, o);
      }
      if (row < N_NODES) {
#pragma unroll
        for (int j = 0; j < 4; ++j)
          hb[(size_t)row * NHD + wn + j * 16 + dl] = f2bf(acc[i][j][q]);
        if (dl == 0) {
          s_src[row * 8 + h0] = ss0;
          s_src[row * 8 + h1] = ss1;
          s_dst[row * 8 + h0] = sd0;
          s_dst[row * 8 + h1] = sd1;
        }
      }
    }
  }
}

// ---- CSR build: per-block degree sums (196 blocks x 256)
__global__ __launch_bounds__(256) void k_bsum(const int* __restrict__ deg,
                                              int* __restrict__ bsum) {
  __shared__ int sm[4];
  int i = blockIdx.x * 256 + threadIdx.x;
  int v = (i < N_NODES) ? deg[i] : 0;
#pragma unroll
  for (int o = 1; o < 64; o <<= 1) v += __shfl_xor(v, o);
  if ((threadIdx.x & 63) == 0) sm[threadIdx.x >> 6] = v;
  __syncthreads();
  if (threadIdx.x == 0) bsum[blockIdx.x] = sm[0] + sm[1] + sm[2] + sm[3];
}

// full scan: each block re-scans the 196 block sums, then its 256 degrees
__global__ __launch_bounds__(256) void k_scan_main(const int* __restrict__ deg,
                                                   const int* __restrict__ bsum,
                                                   int* __restrict__ rowptr,
                                                   int* __restrict__ cursor) {
  __shared__ int sb[256];
  __shared__ int sm[256];
  const int t = threadIdx.x;
  const int b = blockIdx.x;
  int bv = (t < N_SBLK) ? bsum[t] : 0;
  sb[t] = bv;
  int i = b * 256 + t;
  int v = (i < N_NODES) ? deg[i] : 0;
  sm[t] = v;
  __syncthreads();
#pragma unroll
  for (int o = 1; o < 256; o <<= 1) {
    int u1 = (t >= o) ? sb[t - o] : 0;
    int u2 = (t >= o) ? sm[t - o] : 0;
    __syncthreads();
    sb[t] += u1;
    sm[t] += u2;
    __syncthreads();
  }
  int boff = (b > 0) ? sb[b - 1] : 0;
  if (i < N_NODES) {
    int ex = boff + sm[t] - v;
    rowptr[i] = ex;
    cursor[i] = ex;
  }
  if (b == 0 && t == 0) rowptr[N_NODES] = sb[255];
}

__global__ void k_fill(const int* __restrict__ ei, int* __restrict__ cursor,
                       int* __restrict__ edst) {
  int e = blockIdx.x * blockDim.x + threadIdx.x;
  if (e >= N_EDGES) return;
  int p = atomicAdd(&cursor[ei[e]], 1);
  edst[p] = ei[N_EDGES + e];
}

// ---- fused aggregation: one wave per node, m=0 softmax, 2-way unrolled
__global__ __launch_bounds__(256) void k_aggr(const int* __restrict__ rowptr,
                                              const int* __restrict__ edst,
                                              const float* __restrict__ s_src,
                                              const float* __restrict__ s_dst,
                                              const unsigned short* __restrict__ hb,
                                              float* __restrict__ out) {
  int n = (int)((blockIdx.x * blockDim.x + threadIdx.x) >> 6);
  if (n >= N_NODES) return;
  n = __builtin_amdgcn_readfirstlane(n);
  const int lane = threadIdx.x & 63;
  const int head = lane >> 3;
  const float ssrc = s_src[n * 8 + head];
  int i = rowptr[n];
  const int iend = rowptr[n + 1];
  float den = 0.f;
  f32x4 acc = {0.f, 0.f, 0.f, 0.f};
  for (; i + 1 < iend; i += 2) {
    int d0 = edst[i], d1 = edst[i + 1];
    float v0 = ssrc + s_dst[d0 * 8 + head];
    float v1 = ssrc + s_dst[d1 * 8 + head];
    u16x4 h0 = *(const u16x4*)(hb + (size_t)d0 * NHD + lane * 4);
    u16x4 h1 = *(const u16x4*)(hb + (size_t)d1 * NHD + lane * 4);
    v0 = v0 >= 0.f ? v0 : SLOPE * v0;
    v1 = v1 >= 0.f ? v1 : SLOPE * v1;
    float e0 = __expf(v0), e1 = __expf(v1);
    den += e0 + e1;
    acc.x += e0 * bf2f(h0.x) + e1 * bf2f(h1.x);
    acc.y += e0 * bf2f(h0.y) + e1 * bf2f(h1.y);
    acc.z += e0 * bf2f(h0.z) + e1 * bf2f(h1.z);
    acc.w += e0 * bf2f(h0.w) + e1 * bf2f(h1.w);
  }
  if (i < iend) {
    int d0 = edst[i];
    float v0 = ssrc + s_dst[d0 * 8 + head];
    v0 = v0 >= 0.f ? v0 : SLOPE * v0;
    float e0 = __expf(v0);
    u16x4 h0 = *(const u16x4*)(hb + (size_t)d0 * NHD + lane * 4);
    den += e0;
    acc.x += e0 * bf2f(h0.x);
    acc.y += e0 * bf2f(h0.y);
    acc.z += e0 * bf2f(h0.z);
    acc.w += e0 * bf2f(h0.w);
  }
  float inv = 1.f / (den + EPS_F);         // deg==0: acc=0 -> out=0
  *(f32x4*)(out + (size_t)n * NHD + lane * 4) = acc * inv;
}

extern "C" void kernel_launch(void* const* d_in, const int* in_sizes, int n_in,
                              void* d_out, int out_size, void* d_ws, size_t ws_size,
                              hipStream_t stream) {
  const float* x  = (const float*)d_in[0];
  const int*   ei = (const int*)d_in[1];
  const float* W  = (const float*)d_in[2];
  const float* a  = (const float*)d_in[3];
  float* out = (float*)d_out;

  // workspace layout (~33 MB, 16B-aligned blocks)
  unsigned short* hb  = (unsigned short*)d_ws;                 // 12,800,000 u16
  unsigned short* WbT = hb + (size_t)N_NODES * NHD;            // 131,072 u16
  float* s_src = (float*)(WbT + (size_t)NHD * IN_F);           // 400,000 f
  float* s_dst = s_src + (size_t)N_NODES * HEADS;              // 400,000 f
  int* deg    = (int*)(s_dst + (size_t)N_NODES * HEADS);       // 50,000
  int* cursor = deg + N_NODES;                                 // 50,000
  int* rowptr = cursor + N_NODES;                              // 50,001 (pad 50,008)
  int* bsum   = rowptr + 50008;                                // 196 (pad 256)
  int* edst   = bsum + 256;                                    // 800,000

  k_cast_w<<<512, 256, 0, stream>>>(W, WbT, deg);
  k_gemm_mfma<<<NB_GEMM + NB_HIST, 256, 0, stream>>>(x, WbT, hb, a, s_src, s_dst, ei, deg);
  k_bsum<<<N_SBLK, 256, 0, stream>>>(deg, bsum);
  k_scan_main<<<N_SBLK, 256, 0, stream>>>(deg, bsum, rowptr, cursor);
  k_fill<<<(N_EDGES + 255) / 256, 256, 0, stream>>>(ei, cursor, edst);
  k_aggr<<<(N_NODES * 64 + 255) / 256, 256, 0, stream>>>(rowptr, edst, s_src, s_dst, hb, out);
}

// Round 11
// 184.329 us; speedup vs baseline: 1.0582x; 1.0582x over previous
//
#include <hip/hip_runtime.h>
#include <hip/hip_bf16.h>

#define N_NODES 50000
#define N_EDGES 800000
#define IN_F    512
#define HEADS   8
#define DHEAD   32
#define NHD     256            // HEADS*DHEAD
#define SLOPE   0.2f
#define EPS_F   1e-16f
#define N_SBLK  ((N_NODES + 255) / 256)   // 196 scan blocks
#define NB_GEMM ((N_NODES + 63) / 64)     // 782 gemm blocks
#define NB_HIST ((N_EDGES + 4095) / 4096) // 196 hist blocks (4096 edges each)

typedef __attribute__((ext_vector_type(8))) short short8;
typedef __attribute__((ext_vector_type(4))) float f32x4;
typedef __attribute__((ext_vector_type(4))) unsigned short u16x4;
typedef __attribute__((ext_vector_type(4))) unsigned int u32x4;

__device__ __forceinline__ unsigned short f2bf(float f) {
  unsigned int u = __float_as_uint(f);
  unsigned int r = u + 0x7FFFu + ((u >> 16) & 1u);   // round-to-nearest-even
  return (unsigned short)(r >> 16);
}
__device__ __forceinline__ float bf2f(unsigned short s) {
  return __uint_as_float(((unsigned int)s) << 16);
}
// packed f32x2 -> bf16x2 (v_cvt_pk_bf16_f32, RNE)
__device__ __forceinline__ unsigned int pkbf(float a, float b) {
  __hip_bfloat162 t = __float22bfloat162_rn(float2{a, b});
  unsigned int r;
  __builtin_memcpy(&r, &t, sizeof(r));
  return r;
}
__device__ __forceinline__ void gload_lds16(const void* g, void* l) {
  __builtin_amdgcn_global_load_lds((const __attribute__((address_space(1))) void*)g,
                                   (__attribute__((address_space(3))) void*)l, 16, 0, 0);
}

// ---- cast W[h][k][d] (f32) -> WbT[c][k] (bf16), c = h*32+d; also zero deg
__global__ void k_cast_w(const float* __restrict__ W, unsigned short* __restrict__ WbT,
                         int* __restrict__ deg) {
  int id = blockIdx.x * blockDim.x + threadIdx.x;
  if (id < NHD * IN_F) {
    int c = id >> 9, k = id & 511;
    WbT[id] = f2bf(W[(c >> 5) * (IN_F * DHEAD) + k * DHEAD + (c & 31)]);
  }
  if (id < N_NODES) deg[id] = 0;
}

// ---- MFMA GEMM (blocks 0..781) + edge histogram (blocks 782..977).
// Tile 64(M)x256(N), BK=32, 4 waves, single-buffer LDS = 20 KB
// -> 8 blocks/CU co-resident (TLP hides the staging latency; R10's 40 KB
// gave only ~1.7 effective blocks/CU and 90 us of barrier stalls).
// LDS rows of 4 16B-quads, slot p = q ^ ((row>>1)&3) -> reads 2-way = free.
// Epilogue fuses s_src/s_dst score dots from f32 accumulators.
__global__ __launch_bounds__(256) void k_gemm_mfma(const float* __restrict__ x,
                                                   const unsigned short* __restrict__ WbT,
                                                   unsigned short* __restrict__ hb,
                                                   const float* __restrict__ a,
                                                   float* __restrict__ s_src,
                                                   float* __restrict__ s_dst,
                                                   const int* __restrict__ ei,
                                                   int* __restrict__ deg) {
  if (blockIdx.x >= NB_GEMM) {            // ---- histogram path (overlapped)
    int b = blockIdx.x - NB_GEMM;
    int end = min(b * 4096 + 4096, N_EDGES);
    for (int e = b * 4096 + threadIdx.x; e < end; e += 256)
      atomicAdd(&deg[ei[e]], 1);
    return;
  }

  __shared__ unsigned short As[64 * 32];    // 4 KB
  __shared__ unsigned short Bs[256 * 32];   // 16 KB
  const int tid  = threadIdx.x;
  const int lane = tid & 63;
  const int wid  = tid >> 6;
  const int bm   = blockIdx.x * 64;
  const int wn   = wid * 64;

  // A staging: 256 slots (64 rows x 4 quads), one 16B quad per thread
  const int arow = tid >> 2, ap = tid & 3, aq = ap ^ ((arow >> 1) & 3);
  const float* gA = x + (size_t)min(bm + arow, N_NODES - 1) * IN_F + aq * 8;
  unsigned short* lA = &As[(arow * 4 + ap) * 8];

  // B staging (async gload_lds): wave wid stages slots 256*wid + 64*it + lane
  const int brow0 = 64 * wid + (lane >> 2);
  const int bq = (lane & 3) ^ ((lane >> 3) & 3);   // ((brow0>>1)&3) == ((lane>>3)&3)
  const unsigned short* gB0 = WbT + (size_t)brow0 * IN_F + bq * 8;
  unsigned short* lBw = &Bs[((size_t)256 * wid + lane) * 8];

  f32x4 acc[4][4] = {};

#pragma unroll
  for (int t = 0; t < 16; ++t) {
    const int k0 = t * 32;
    __syncthreads();                      // prev-step LDS reads done
#pragma unroll
    for (int it = 0; it < 4; ++it)        // B: 4 x gload_lds (16 rows each)
      gload_lds16(gB0 + k0 + it * 16 * IN_F, lBw + it * 64 * 8);
    {                                     // A: 8 f32 -> 1 x b128 LDS write
      float4 lo = *(const float4*)(gA + k0);
      float4 hi = *(const float4*)(gA + k0 + 4);
      u32x4 v = { pkbf(lo.x, lo.y), pkbf(lo.z, lo.w),
                  pkbf(hi.x, hi.y), pkbf(hi.z, hi.w) };
      *(u32x4*)lA = v;
    }
    __syncthreads();                      // staging visible

    const int dl = lane & 15;
    const int p  = (lane >> 4) ^ ((dl >> 1) & 3);  // physical quad slot
    short8 af[4], bfr[4];
#pragma unroll
    for (int i = 0; i < 4; ++i)
      af[i] = *(const short8*)&As[((i * 16 + dl) * 4 + p) * 8];
#pragma unroll
    for (int j = 0; j < 4; ++j)
      bfr[j] = *(const short8*)&Bs[((wn + j * 16 + dl) * 4 + p) * 8];
#pragma unroll
    for (int i = 0; i < 4; ++i)
#pragma unroll
      for (int j = 0; j < 4; ++j)
        acc[i][j] = __builtin_amdgcn_mfma_f32_16x16x32_bf16(af[i], bfr[j], acc[i][j], 0, 0, 0);
  }

  // ---- epilogue: hb (bf16) write + fused scores from f32 acc
  // C/D layout: col = lane&15, row = (lane>>4)*4 + q
  const int h0 = 2 * wid, h1 = 2 * wid + 1;
  const int dl = lane & 15;
  const float as00 = a[h0 * 64 + dl],      as01 = a[h0 * 64 + 16 + dl];
  const float as10 = a[h1 * 64 + dl],      as11 = a[h1 * 64 + 16 + dl];
  const float ad00 = a[h0 * 64 + 32 + dl], ad01 = a[h0 * 64 + 48 + dl];
  const float ad10 = a[h1 * 64 + 32 + dl], ad11 = a[h1 * 64 + 48 + dl];

#pragma unroll
  for (int i = 0; i < 4; ++i) {
#pragma unroll
    for (int q = 0; q < 4; ++q) {
      int row = bm + i * 16 + (lane >> 4) * 4 + q;
      float ss0 = acc[i][0][q] * as00 + acc[i][1][q] * as01;
      float ss1 = acc[i][2][q] * as10 + acc[i][3][q] * as11;
      float sd0 = acc[i][0][q] * ad00 + acc[i][1][q] * ad01;
      float sd1 = acc[i][2][q] * ad10 + acc[i][3][q] * ad11;
#pragma unroll
      for (int o = 1; o < 16; o <<= 1) {
        ss0 += __shfl_xor(ss0, o);
        ss1 += __shfl_xor(ss1, o);
        sd0 += __shfl_xor(sd0, o);
        sd1 += __shfl_xor(sd1, o);
      }
      if (row < N_NODES) {
#pragma unroll
        for (int j = 0; j < 4; ++j)
          hb[(size_t)row * NHD + wn + j * 16 + dl] = f2bf(acc[i][j][q]);
        if (dl == 0) {
          s_src[row * 8 + h0] = ss0;
          s_src[row * 8 + h1] = ss1;
          s_dst[row * 8 + h0] = sd0;
          s_dst[row * 8 + h1] = sd1;
        }
      }
    }
  }
}

// ---- CSR build: per-block degree sums (196 blocks x 256)
__global__ __launch_bounds__(256) void k_bsum(const int* __restrict__ deg,
                                              int* __restrict__ bsum) {
  __shared__ int sm[4];
  int i = blockIdx.x * 256 + threadIdx.x;
  int v = (i < N_NODES) ? deg[i] : 0;
#pragma unroll
  for (int o = 1; o < 64; o <<= 1) v += __shfl_xor(v, o);
  if ((threadIdx.x & 63) == 0) sm[threadIdx.x >> 6] = v;
  __syncthreads();
  if (threadIdx.x == 0) bsum[blockIdx.x] = sm[0] + sm[1] + sm[2] + sm[3];
}

// full scan: each block re-scans the 196 block sums, then its 256 degrees
__global__ __launch_bounds__(256) void k_scan_main(const int* __restrict__ deg,
                                                   const int* __restrict__ bsum,
                                                   int* __restrict__ rowptr,
                                                   int* __restrict__ cursor) {
  __shared__ int sb[256];
  __shared__ int sm[256];
  const int t = threadIdx.x;
  const int b = blockIdx.x;
  int bv = (t < N_SBLK) ? bsum[t] : 0;
  sb[t] = bv;
  int i = b * 256 + t;
  int v = (i < N_NODES) ? deg[i] : 0;
  sm[t] = v;
  __syncthreads();
#pragma unroll
  for (int o = 1; o < 256; o <<= 1) {
    int u1 = (t >= o) ? sb[t - o] : 0;
    int u2 = (t >= o) ? sm[t - o] : 0;
    __syncthreads();
    sb[t] += u1;
    sm[t] += u2;
    __syncthreads();
  }
  int boff = (b > 0) ? sb[b - 1] : 0;
  if (i < N_NODES) {
    int ex = boff + sm[t] - v;
    rowptr[i] = ex;
    cursor[i] = ex;
  }
  if (b == 0 && t == 0) rowptr[N_NODES] = sb[255];
}

__global__ void k_fill(const int* __restrict__ ei, int* __restrict__ cursor,
                       int* __restrict__ edst) {
  int e = blockIdx.x * blockDim.x + threadIdx.x;
  if (e >= N_EDGES) return;
  int p = atomicAdd(&cursor[ei[e]], 1);
  edst[p] = ei[N_EDGES + e];
}

// ---- fused aggregation: one wave per node, m=0 softmax, 2-way unrolled
__global__ __launch_bounds__(256) void k_aggr(const int* __restrict__ rowptr,
                                              const int* __restrict__ edst,
                                              const float* __restrict__ s_src,
                                              const float* __restrict__ s_dst,
                                              const unsigned short* __restrict__ hb,
                                              float* __restrict__ out) {
  int n = (int)((blockIdx.x * blockDim.x + threadIdx.x) >> 6);
  if (n >= N_NODES) return;
  n = __builtin_amdgcn_readfirstlane(n);
  const int lane = threadIdx.x & 63;
  const int head = lane >> 3;
  const float ssrc = s_src[n * 8 + head];
  int i = rowptr[n];
  const int iend = rowptr[n + 1];
  float den = 0.f;
  f32x4 acc = {0.f, 0.f, 0.f, 0.f};
  for (; i + 1 < iend; i += 2) {
    int d0 = edst[i], d1 = edst[i + 1];
    float v0 = ssrc + s_dst[d0 * 8 + head];
    float v1 = ssrc + s_dst[d1 * 8 + head];
    u16x4 h0 = *(const u16x4*)(hb + (size_t)d0 * NHD + lane * 4);
    u16x4 h1 = *(const u16x4*)(hb + (size_t)d1 * NHD + lane * 4);
    v0 = v0 >= 0.f ? v0 : SLOPE * v0;
    v1 = v1 >= 0.f ? v1 : SLOPE * v1;
    float e0 = __expf(v0), e1 = __expf(v1);
    den += e0 + e1;
    acc.x += e0 * bf2f(h0.x) + e1 * bf2f(h1.x);
    acc.y += e0 * bf2f(h0.y) + e1 * bf2f(h1.y);
    acc.z += e0 * bf2f(h0.z) + e1 * bf2f(h1.z);
    acc.w += e0 * bf2f(h0.w) + e1 * bf2f(h1.w);
  }
  if (i < iend) {
    int d0 = edst[i];
    float v0 = ssrc + s_dst[d0 * 8 + head];
    v0 = v0 >= 0.f ? v0 : SLOPE * v0;
    float e0 = __expf(v0);
    u16x4 h0 = *(const u16x4*)(hb + (size_t)d0 * NHD + lane * 4);
    den += e0;
    acc.x += e0 * bf2f(h0.x);
    acc.y += e0 * bf2f(h0.y);
    acc.z += e0 * bf2f(h0.z);
    acc.w += e0 * bf2f(h0.w);
  }
  float inv = 1.f / (den + EPS_F);         // deg==0: acc=0 -> out=0
  *(f32x4*)(out + (size_t)n * NHD + lane * 4) = acc * inv;
}

extern "C" void kernel_launch(void* const* d_in, const int* in_sizes, int n_in,
                              void* d_out, int out_size, void* d_ws, size_t ws_size,
                              hipStream_t stream) {
  const float* x  = (const float*)d_in[0];
  const int*   ei = (const int*)d_in[1];
  const float* W  = (const float*)d_in[2];
  const float* a  = (const float*)d_in[3];
  float* out = (float*)d_out;

  // workspace layout (~33 MB, 16B-aligned blocks)
  unsigned short* hb  = (unsigned short*)d_ws;                 // 12,800,000 u16
  unsigned short* WbT = hb + (size_t)N_NODES * NHD;            // 131,072 u16
  float* s_src = (float*)(WbT + (size_t)NHD * IN_F);           // 400,000 f
  float* s_dst = s_src + (size_t)N_NODES * HEADS;              // 400,000 f
  int* deg    = (int*)(s_dst + (size_t)N_NODES * HEADS);       // 50,000
  int* cursor = deg + N_NODES;                                 // 50,000
  int* rowptr = cursor + N_NODES;                              // 50,001 (pad 50,008)
  int* bsum   = rowptr + 50008;                                // 196 (pad 256)
  int* edst   = bsum + 256;                                    // 800,000

  k_cast_w<<<512, 256, 0, stream>>>(W, WbT, deg);
  k_gemm_mfma<<<NB_GEMM + NB_HIST, 256, 0, stream>>>(x, WbT, hb, a, s_src, s_dst, ei, deg);
  k_bsum<<<N_SBLK, 256, 0, stream>>>(deg, bsum);
  k_scan_main<<<N_SBLK, 256, 0, stream>>>(deg, bsum, rowptr, cursor);
  k_fill<<<(N_EDGES + 255) / 256, 256, 0, stream>>>(ei, cursor, edst);
  k_aggr<<<(N_NODES * 64 + 255) / 256, 256, 0, stream>>>(rowptr, edst, s_src, s_dst, hb, out);
}